// Round 5
// baseline (623.943 us; speedup 1.0000x reference)
//
#include <hip/hip_runtime.h>
#include <hip/hip_bf16.h>
#include <math.h>

#define NN 4096
#define BB 4
#define CC 64
#define ICH 32
#define NSPL 8              // K-splits per block (within-block, LDS-combined)
#define KRANGE (NN / NSPL)  // 512 K rows per split
#define RPB 32              // Q rows per block
#define MTILE 8             // K rows per online-softmax tile

// workspace layout (float offsets); total exactly 8 MB.
// WY (B*C*N floats) aliases Q+K (dead after attn); AB aliases V (dead after attn).
#define OFF_Q    0
#define OFF_K    (OFF_Q + BB * NN * ICH)   //  524288
#define OFF_V    (OFF_K + BB * NN * ICH)   // 1048576
#define OFF_Y    (OFF_V + BB * NN * ICH)   // 1572864
#define OFF_WY   0
#define OFF_AB   OFF_V

// ---------------------------------------------------------------------------
// Kernel 1: projections.  Q = phi(x_other), K = theta(x_this), V = g(x_this)
// out layout [b][n][i] fp32.  x layout (N,B,C): elem (n*B+b)*C + c
// ---------------------------------------------------------------------------
__global__ __launch_bounds__(256) void proj_kernel(
    const float* __restrict__ xt, const float* __restrict__ xo,
    const float* __restrict__ gw, const float* __restrict__ gb,
    const float* __restrict__ tw, const float* __restrict__ tb,
    const float* __restrict__ pw, const float* __restrict__ pb,
    float* __restrict__ Q, float* __restrict__ K, float* __restrict__ V) {
  __shared__ float wth[ICH * 65];  // pad 65: banks (i+c)%32, conflict-free
  __shared__ float wgg[ICH * 65];
  __shared__ float wph[ICH * 65];
  __shared__ float bth[ICH], bgg[ICH], bph[ICH];
  __shared__ float xs_t[8 * 64], xs_o[8 * 64];

  int tid = threadIdx.x;
  for (int l = tid; l < ICH * CC; l += 256) {
    int i = l >> 6, c = l & 63;
    wth[i * 65 + c] = tw[l];
    wgg[i * 65 + c] = gw[l];
    wph[i * 65 + c] = pw[l];
  }
  if (tid < ICH) {
    bth[tid] = tb[tid];
    bgg[tid] = gb[tid];
    bph[tid] = pb[tid];
  }
  int nb0 = blockIdx.x * 8;  // 8 (n,b) rows per block
  for (int l = tid; l < 8 * 64; l += 256) {
    int nb = nb0 + (l >> 6);
    int c = l & 63;
    xs_t[l] = xt[(size_t)nb * 64 + c];
    xs_o[l] = xo[(size_t)nb * 64 + c];
  }
  __syncthreads();

  int i = tid & 31, dnb = tid >> 5;
  int nb = nb0 + dnb;
  int b = nb & (BB - 1);
  int n = nb >> 2;
  float at = bth[i], ag = bgg[i], ap = bph[i];
  for (int c = 0; c < CC; c++) {
    float xv = xs_t[dnb * 64 + c];
    float xvo = xs_o[dnb * 64 + c];
    at += wth[i * 65 + c] * xv;
    ag += wgg[i * 65 + c] * xv;
    ap += wph[i * 65 + c] * xvo;
  }
  size_t outi = ((size_t)b * NN + n) * ICH + i;
  K[outi] = at;
  V[outi] = ag;
  Q[outi] = ap;
}

// ---------------------------------------------------------------------------
// Kernel 2: flash attention, split-K within block, serial-per-row combine.
// 256 threads = 32 Q rows x 8 splits; partials merged through LDS.
// ---------------------------------------------------------------------------
__global__ __launch_bounds__(256) void attn_kernel(
    const float* __restrict__ Q, const float* __restrict__ Km,
    const float* __restrict__ V, float* __restrict__ Y) {
  __shared__ float lo[NSPL * RPB * 33];  // per (split,row): o[32], pad 33
  __shared__ float lm[NSPL * RPB];
  __shared__ float ll[NSPL * RPB];

  int t = threadIdx.x;
  int b = blockIdx.y;
  int bn0 = blockIdx.x * RPB;
  int r = t & 31, s = t >> 5;

  const float4* Qv = (const float4*)(Q + ((size_t)b * NN + bn0 + r) * ICH);
  float q[ICH];
#pragma unroll
  for (int j = 0; j < 8; j++) {
    float4 tq = Qv[j];
    q[4 * j + 0] = tq.x; q[4 * j + 1] = tq.y;
    q[4 * j + 2] = tq.z; q[4 * j + 3] = tq.w;
  }
  float o[ICH];
#pragma unroll
  for (int i = 0; i < ICH; i++) o[i] = 0.f;
  float mrun = -1e30f, lrun = 0.f;

  const float4* Kb = (const float4*)(Km + ((size_t)b * NN) * ICH);
  const float4* Vb = (const float4*)(V + ((size_t)b * NN) * ICH);
  int m0 = s * KRANGE;
  for (int tt = 0; tt < KRANGE / MTILE; tt++) {  // 64 tiles of 8 K rows
    const float4* Kg = Kb + (size_t)(m0 + tt * MTILE) * 8;
    const float4* Vg = Vb + (size_t)(m0 + tt * MTILE) * 8;
    float sc[MTILE];
    float tmax = -1e30f;
#pragma unroll
    for (int rr = 0; rr < MTILE; rr++) {
      float acc = 0.f;
#pragma unroll
      for (int j = 0; j < 8; j++) {
        float4 kv = Kg[rr * 8 + j];
        acc += q[4 * j + 0] * kv.x + q[4 * j + 1] * kv.y +
               q[4 * j + 2] * kv.z + q[4 * j + 3] * kv.w;
      }
      sc[rr] = acc;
      tmax = fmaxf(tmax, acc);
    }
    float newm = fmaxf(mrun, tmax);
    float alpha = __expf(mrun - newm);  // finite args always
    lrun *= alpha;
#pragma unroll
    for (int i = 0; i < ICH; i++) o[i] *= alpha;
#pragma unroll
    for (int rr = 0; rr < MTILE; rr++) {
      float p = __expf(sc[rr] - newm);
      lrun += p;
#pragma unroll
      for (int j = 0; j < 8; j++) {
        float4 vv = Vg[rr * 8 + j];
        o[4 * j + 0] += p * vv.x; o[4 * j + 1] += p * vv.y;
        o[4 * j + 2] += p * vv.z; o[4 * j + 3] += p * vv.w;
      }
    }
    mrun = newm;
  }

  int sr = s * RPB + r;
#pragma unroll
  for (int i = 0; i < ICH; i++) lo[sr * 33 + i] = o[i];
  lm[sr] = mrun;
  ll[sr] = lrun;
  __syncthreads();

  // serial combine: thread t<32 owns row t entirely.
  if (t < RPB) {
    float mstar = -1e30f;
#pragma unroll
    for (int ss = 0; ss < NSPL; ss++) mstar = fmaxf(mstar, lm[ss * RPB + t]);
    float L = 0.f;
    float acc[ICH];
#pragma unroll
    for (int i = 0; i < ICH; i++) acc[i] = 0.f;
#pragma unroll
    for (int ss = 0; ss < NSPL; ss++) {
      float wgt = __expf(lm[ss * RPB + t] - mstar);
      L += wgt * ll[ss * RPB + t];
      const float* op = lo + (ss * RPB + t) * 33;
#pragma unroll
      for (int i = 0; i < ICH; i++) acc[i] += wgt * op[i];
    }
    float invL = 1.f / L;
    float4* Yo = (float4*)(Y + ((size_t)b * NN + bn0 + t) * ICH);
#pragma unroll
    for (int j = 0; j < 8; j++)
      Yo[j] = make_float4(acc[4 * j + 0] * invL, acc[4 * j + 1] * invL,
                          acc[4 * j + 2] * invL, acc[4 * j + 3] * invL);
  }
}

// ---------------------------------------------------------------------------
// Kernel 3: wz projection, materialized: WY[b,c,n] = w_c . Y[b,n,:] + bc
// ---------------------------------------------------------------------------
__global__ __launch_bounds__(256) void wz_kernel(
    const float* __restrict__ Y, const float* __restrict__ wz_w,
    const float* __restrict__ wz_b, float* __restrict__ WY) {
  __shared__ float yl[64 * 33];
  __shared__ float w[CC * ICH];
  __shared__ float bias[CC];
  int b = blockIdx.y;
  int n0 = blockIdx.x * 64;
  int t = threadIdx.x;
  for (int l = t; l < CC * ICH; l += 256) w[l] = wz_w[l];
  if (t < CC) bias[t] = wz_b[t];
#pragma unroll
  for (int it = 0; it < 8; it++) {
    int lin = it * 256 + t;
    int i = lin & 31, dn = lin >> 5;
    yl[dn * 33 + i] = Y[((size_t)b * NN + n0 + dn) * ICH + i];
  }
  __syncthreads();
#pragma unroll
  for (int it = 0; it < 16; it++) {
    int lin = it * 256 + t;
    int c = lin >> 6, dn = lin & 63;
    float acc = bias[c];
#pragma unroll
    for (int i = 0; i < ICH; i++) acc += w[c * 32 + i] * yl[dn * 33 + i];
    WY[((size_t)(b * CC + c)) * NN + n0 + dn] = acc;
  }
}

// ---------------------------------------------------------------------------
// Kernel 4: BN stats per channel from materialized WY. fp64, deterministic.
// AB[c] = gamma*rstd ; AB[64+c] = beta - mean*gamma*rstd
// ---------------------------------------------------------------------------
__global__ __launch_bounds__(256) void stats_kernel(
    const float* __restrict__ WY, const float* __restrict__ gamma,
    const float* __restrict__ beta, float* __restrict__ AB) {
  int c = blockIdx.x;
  int t = threadIdx.x;
  double s = 0.0, s2 = 0.0;
  for (int b = 0; b < BB; b++) {
    const float* p = WY + ((size_t)(b * CC + c)) * NN;
    for (int n = t; n < NN; n += 256) {
      double v = (double)p[n];
      s += v;
      s2 += v * v;
    }
  }
  __shared__ double rs[256], rs2[256];
  rs[t] = s;
  rs2[t] = s2;
  __syncthreads();
  for (int off = 128; off > 0; off >>= 1) {
    if (t < off) {
      rs[t] += rs[t + off];
      rs2[t] += rs2[t + off];
    }
    __syncthreads();
  }
  if (t == 0) {
    double inv = 1.0 / (double)(BB * NN);
    double mean = rs[0] * inv;
    double var = rs2[0] * inv - mean * mean;
    if (var < 0.0) var = 0.0;
    double rstd = 1.0 / sqrt(var + 1e-5);
    float A = gamma[c] * (float)rstd;
    AB[c] = A;
    AB[64 + c] = beta[c] - (float)mean * A;
  }
}

// ---------------------------------------------------------------------------
// Kernel 5: normalize + residual -> FP32 out (B,C,N)   [the R4->R5 fix]
// out[b,c,n] = WY[b,c,n]*A_c + AB2_c + x_this[n,b,c]
// ---------------------------------------------------------------------------
__global__ __launch_bounds__(256) void norm_kernel(
    const float* __restrict__ WY, const float* __restrict__ AB,
    const float* __restrict__ xthis, float* __restrict__ out) {
  __shared__ float xl[64 * 65];
  __shared__ float abr[128];
  int b = blockIdx.y, n0 = blockIdx.x * 64, t = threadIdx.x;
  if (t < 128) abr[t] = AB[t];
#pragma unroll
  for (int it = 0; it < 16; it++) {
    int lin = it * 256 + t;
    int c = lin & 63, dn = lin >> 6;  // coalesced over c
    xl[dn * 65 + c] = xthis[((size_t)(n0 + dn) * BB + b) * CC + c];
  }
  __syncthreads();
#pragma unroll
  for (int it = 0; it < 16; it++) {
    int lin = it * 256 + t;
    int c = lin >> 6, dn = lin & 63;  // coalesced over n
    size_t idx = ((size_t)(b * CC + c)) * NN + n0 + dn;
    out[idx] = WY[idx] * abr[c] + abr[64 + c] + xl[dn * 65 + c];
  }
}

// ---------------------------------------------------------------------------
extern "C" void kernel_launch(void* const* d_in, const int* in_sizes, int n_in,
                              void* d_out, int out_size, void* d_ws,
                              size_t ws_size, hipStream_t stream) {
  const float* x_this = (const float*)d_in[0];
  const float* x_other = (const float*)d_in[1];
  const float* g_w = (const float*)d_in[2];
  const float* g_b = (const float*)d_in[3];
  const float* th_w = (const float*)d_in[4];
  const float* th_b = (const float*)d_in[5];
  const float* ph_w = (const float*)d_in[6];
  const float* ph_b = (const float*)d_in[7];
  const float* wz_w = (const float*)d_in[8];
  const float* wz_b = (const float*)d_in[9];
  const float* gamma = (const float*)d_in[10];
  const float* beta = (const float*)d_in[11];
  float* out = (float*)d_out;  // reference output dtype is float32

  float* ws = (float*)d_ws;
  float* Q = ws + OFF_Q;
  float* K = ws + OFF_K;
  float* V = ws + OFF_V;
  float* Y = ws + OFF_Y;
  float* WY = ws + OFF_WY;  // aliases Q+K (dead after attn)
  float* AB = ws + OFF_AB;  // aliases V (dead after attn)

  hipLaunchKernelGGL(proj_kernel, dim3(NN * BB / 8), dim3(256), 0, stream,
                     x_this, x_other, g_w, g_b, th_w, th_b, ph_w, ph_b,
                     Q, K, V);
  hipLaunchKernelGGL(attn_kernel, dim3(NN / RPB, BB), dim3(256), 0, stream,
                     Q, K, V, Y);
  hipLaunchKernelGGL(wz_kernel, dim3(NN / 64, BB), dim3(256), 0, stream,
                     Y, wz_w, wz_b, WY);
  hipLaunchKernelGGL(stats_kernel, dim3(CC), dim3(256), 0, stream,
                     WY, gamma, beta, AB);
  hipLaunchKernelGGL(norm_kernel, dim3(NN / 64, BB), dim3(256), 0, stream,
                     WY, AB, x_this, out);
}

// Round 6
// 172.291 us; speedup vs baseline: 3.6214x; 3.6214x over previous
//
#include <hip/hip_runtime.h>
#include <hip/hip_bf16.h>
#include <math.h>

typedef unsigned short ushort_t;
typedef __attribute__((ext_vector_type(8))) short short8;
typedef __attribute__((ext_vector_type(4))) float float4v;

#define NN 4096
#define BB 4
#define CC 64
#define ICH 32

// workspace layout (float offsets); total 1,572,992 floats = 6.3 MB.
// region0 [0..1048576): phase1 = Qb/Kb/Vt (bf16), phase2 = WY (fp32, aliases).
#define OFF_QB 0                     // ushort, 524288 elems (262144 floats)
#define OFF_KB 262144                // ushort, 524288 elems
#define OFF_VT 524288                // ushort, 524288 elems (transposed V)
#define OFF_WY 0                     // fp32, 1048576 elems, aliases Qb/Kb/Vt
#define OFF_Y  1048576               // fp32, 524288
#define OFF_AB 1572864               // fp32, 128

static __device__ __forceinline__ ushort_t f2b(float f) {
  union { float f; unsigned u; } v;
  v.f = f;
  return (ushort_t)((v.u + 0x8000u) >> 16);  // round-half-up to bf16
}

// ---------------------------------------------------------------------------
// Kernel 1: projections -> bf16.  Qb = phi(x_other), Kb = theta(x_this),
// Vt = g(x_this) TRANSPOSED [b][i][n].  Qb/Kb layout [b][n][i].
// x layout (N,B,C): elem (n*B+b)*C + c
// ---------------------------------------------------------------------------
__global__ __launch_bounds__(256) void proj_kernel(
    const float* __restrict__ xt, const float* __restrict__ xo,
    const float* __restrict__ gw, const float* __restrict__ gb,
    const float* __restrict__ tw, const float* __restrict__ tb,
    const float* __restrict__ pw, const float* __restrict__ pb,
    ushort_t* __restrict__ Qb, ushort_t* __restrict__ Kb,
    ushort_t* __restrict__ Vt) {
  __shared__ float wth[ICH * 65];
  __shared__ float wgg[ICH * 65];
  __shared__ float wph[ICH * 65];
  __shared__ float bth[ICH], bgg[ICH], bph[ICH];
  __shared__ float xs_t[8 * 64], xs_o[8 * 64];

  int tid = threadIdx.x;
  for (int l = tid; l < ICH * CC; l += 256) {
    int i = l >> 6, c = l & 63;
    wth[i * 65 + c] = tw[l];
    wgg[i * 65 + c] = gw[l];
    wph[i * 65 + c] = pw[l];
  }
  if (tid < ICH) {
    bth[tid] = tb[tid];
    bgg[tid] = gb[tid];
    bph[tid] = pb[tid];
  }
  int nb0 = blockIdx.x * 8;
  for (int l = tid; l < 8 * 64; l += 256) {
    int nb = nb0 + (l >> 6);
    int c = l & 63;
    xs_t[l] = xt[(size_t)nb * 64 + c];
    xs_o[l] = xo[(size_t)nb * 64 + c];
  }
  __syncthreads();

  int i = tid & 31, dnb = tid >> 5;
  int nb = nb0 + dnb;
  int b = nb & (BB - 1);
  int n = nb >> 2;
  float at = bth[i], ag = bgg[i], ap = bph[i];
  for (int c = 0; c < CC; c++) {
    float xv = xs_t[dnb * 64 + c];
    float xvo = xs_o[dnb * 64 + c];
    at += wth[i * 65 + c] * xv;
    ag += wgg[i * 65 + c] * xv;
    ap += wph[i * 65 + c] * xvo;
  }
  size_t outi = ((size_t)b * NN + n) * ICH + i;
  Kb[outi] = f2b(at);
  Qb[outi] = f2b(ap);
  Vt[((size_t)b * ICH + i) * NN + n] = f2b(ag);
}

// ---------------------------------------------------------------------------
// Kernel 2: MFMA flash attention (no-max softmax: scores bounded, clamp 60).
// WG = 256 thr = 4 waves; wave owns 16 Q rows; grid (NN/64, BB) = 256 WGs.
// Per 32-kr chunk: 2 QK MFMAs -> exp -> P via LDS (C->A layout) -> 2 PV MFMAs.
// A-frag: A[m=lane&15][k=quad*8+j]; C/D: row=quad*4+reg, col=lane&15. (m89/m120)
// ---------------------------------------------------------------------------
__global__ __launch_bounds__(256) void attn_kernel(
    const ushort_t* __restrict__ Qb, const ushort_t* __restrict__ Kb,
    const ushort_t* __restrict__ Vt, float* __restrict__ Y) {
  __shared__ ushort_t plds_all[4][16 * 36];  // per-wave P scratch, stride 36

  int t = threadIdx.x;
  int wv = t >> 6, lane = t & 63;
  int l15 = lane & 15, quad = lane >> 4;
  int b = blockIdx.y;
  int q0 = blockIdx.x * 64 + wv * 16;

  ushort_t* plds = plds_all[wv];

  // Q A-frag: lane holds Q[q0+l15][quad*8 .. +8]  (16B coalesced)
  short8 qf = *(const short8*)(Qb + ((size_t)b * NN + q0 + l15) * ICH + quad * 8);

  float4v o0 = {0.f, 0.f, 0.f, 0.f};  // O[q][ch=l15]
  float4v o1 = {0.f, 0.f, 0.f, 0.f};  // O[q][ch=16+l15]
  float ls[4] = {0.f, 0.f, 0.f, 0.f};  // per-lane partial row sums

  const ushort_t* Kbb = Kb + (size_t)b * NN * ICH;
  const ushort_t* Vtb = Vt + (size_t)b * ICH * NN;

#pragma unroll 2
  for (int m0 = 0; m0 < NN; m0 += 32) {
    // K B-frags: lane holds K[m0+l15][quad*8..+8] == B[ch][kr]
    const ushort_t* kp = Kbb + ((size_t)(m0 + l15)) * ICH + quad * 8;
    short8 kf0 = *(const short8*)(kp);
    short8 kf1 = *(const short8*)(kp + 16 * ICH);
    // V B-frags: lane holds Vt[ch=l15][m0+quad*8..+8] == B[kr][ch]
    const ushort_t* vp = Vtb + (size_t)l15 * NN + m0 + quad * 8;
    short8 vf0 = *(const short8*)(vp);
    short8 vf1 = *(const short8*)(vp + 16 * NN);

    float4v z = {0.f, 0.f, 0.f, 0.f};
    float4v s0 = __builtin_amdgcn_mfma_f32_16x16x32_bf16(qf, kf0, z, 0, 0, 0);
    float4v s1 = __builtin_amdgcn_mfma_f32_16x16x32_bf16(qf, kf1, z, 0, 0, 0);

    // p = exp(s) unnormalized; accumulate per-lane row-sum partials
#pragma unroll
    for (int r = 0; r < 4; r++) {
      float p0 = __expf(fminf(s0[r], 60.f));
      float p1 = __expf(fminf(s1[r], 60.f));
      ls[r] += p0 + p1;
      // C-layout -> LDS: P[q=quad*4+r][kr=l15] and [kr=16+l15]
      plds[(quad * 4 + r) * 36 + l15] = f2b(p0);
      plds[(quad * 4 + r) * 36 + 16 + l15] = f2b(p1);
    }
    // A-layout read: lane needs P[q=l15][kr=quad*8+j], j=0..7 (2x 8B reads)
    typedef __attribute__((ext_vector_type(4))) short short4v;
    const ushort_t* pr = plds + l15 * 36 + quad * 8;
    short4v pa = *(const short4v*)(pr);
    short4v pb2 = *(const short4v*)(pr + 4);
    short8 pf = __builtin_shufflevector(pa, pb2, 0, 1, 2, 3, 4, 5, 6, 7);

    o0 = __builtin_amdgcn_mfma_f32_16x16x32_bf16(pf, vf0, o0, 0, 0, 0);
    o1 = __builtin_amdgcn_mfma_f32_16x16x32_bf16(pf, vf1, o1, 0, 0, 0);
  }

  // reduce row sums across the 16-lane col group (xor masks 1,2,4,8)
#pragma unroll
  for (int r = 0; r < 4; r++) {
    float v = ls[r];
    v += __shfl_xor(v, 1, 64);
    v += __shfl_xor(v, 2, 64);
    v += __shfl_xor(v, 4, 64);
    v += __shfl_xor(v, 8, 64);
    ls[r] = v;
  }

  // write Y[b][q][ch] fp32, normalized
#pragma unroll
  for (int r = 0; r < 4; r++) {
    int q = q0 + quad * 4 + r;
    float inv = 1.f / ls[r];
    float* yp = Y + ((size_t)b * NN + q) * ICH;
    yp[l15] = o0[r] * inv;
    yp[16 + l15] = o1[r] * inv;
  }
}

// ---------------------------------------------------------------------------
// Kernel 3: wz projection: WY[b,c,n] = w_c . Y[b,n,:] + bc   (unchanged)
// ---------------------------------------------------------------------------
__global__ __launch_bounds__(256) void wz_kernel(
    const float* __restrict__ Y, const float* __restrict__ wz_w,
    const float* __restrict__ wz_b, float* __restrict__ WY) {
  __shared__ float yl[64 * 33];
  __shared__ float w[CC * ICH];
  __shared__ float bias[CC];
  int b = blockIdx.y;
  int n0 = blockIdx.x * 64;
  int t = threadIdx.x;
  for (int l = t; l < CC * ICH; l += 256) w[l] = wz_w[l];
  if (t < CC) bias[t] = wz_b[t];
#pragma unroll
  for (int it = 0; it < 8; it++) {
    int lin = it * 256 + t;
    int i = lin & 31, dn = lin >> 5;
    yl[dn * 33 + i] = Y[((size_t)b * NN + n0 + dn) * ICH + i];
  }
  __syncthreads();
#pragma unroll
  for (int it = 0; it < 16; it++) {
    int lin = it * 256 + t;
    int c = lin >> 6, dn = lin & 63;
    float acc = bias[c];
#pragma unroll
    for (int i = 0; i < ICH; i++) acc += w[c * 32 + i] * yl[dn * 33 + i];
    WY[((size_t)(b * CC + c)) * NN + n0 + dn] = acc;
  }
}

// ---------------------------------------------------------------------------
// Kernel 4: BN stats per channel, fp64 deterministic (unchanged)
// ---------------------------------------------------------------------------
__global__ __launch_bounds__(256) void stats_kernel(
    const float* __restrict__ WY, const float* __restrict__ gamma,
    const float* __restrict__ beta, float* __restrict__ AB) {
  int c = blockIdx.x;
  int t = threadIdx.x;
  double s = 0.0, s2 = 0.0;
  for (int b = 0; b < BB; b++) {
    const float* p = WY + ((size_t)(b * CC + c)) * NN;
    for (int n = t; n < NN; n += 256) {
      double v = (double)p[n];
      s += v;
      s2 += v * v;
    }
  }
  __shared__ double rs[256], rs2[256];
  rs[t] = s;
  rs2[t] = s2;
  __syncthreads();
  for (int off = 128; off > 0; off >>= 1) {
    if (t < off) {
      rs[t] += rs[t + off];
      rs2[t] += rs2[t + off];
    }
    __syncthreads();
  }
  if (t == 0) {
    double inv = 1.0 / (double)(BB * NN);
    double mean = rs[0] * inv;
    double var = rs2[0] * inv - mean * mean;
    if (var < 0.0) var = 0.0;
    double rstd = 1.0 / sqrt(var + 1e-5);
    float A = gamma[c] * (float)rstd;
    AB[c] = A;
    AB[64 + c] = beta[c] - (float)mean * A;
  }
}

// ---------------------------------------------------------------------------
// Kernel 5: normalize + residual -> fp32 out (B,C,N)  (unchanged)
// ---------------------------------------------------------------------------
__global__ __launch_bounds__(256) void norm_kernel(
    const float* __restrict__ WY, const float* __restrict__ AB,
    const float* __restrict__ xthis, float* __restrict__ out) {
  __shared__ float xl[64 * 65];
  __shared__ float abr[128];
  int b = blockIdx.y, n0 = blockIdx.x * 64, t = threadIdx.x;
  if (t < 128) abr[t] = AB[t];
#pragma unroll
  for (int it = 0; it < 16; it++) {
    int lin = it * 256 + t;
    int c = lin & 63, dn = lin >> 6;
    xl[dn * 65 + c] = xthis[((size_t)(n0 + dn) * BB + b) * CC + c];
  }
  __syncthreads();
#pragma unroll
  for (int it = 0; it < 16; it++) {
    int lin = it * 256 + t;
    int c = lin >> 6, dn = lin & 63;
    size_t idx = ((size_t)(b * CC + c)) * NN + n0 + dn;
    out[idx] = WY[idx] * abr[c] + abr[64 + c] + xl[dn * 65 + c];
  }
}

// ---------------------------------------------------------------------------
extern "C" void kernel_launch(void* const* d_in, const int* in_sizes, int n_in,
                              void* d_out, int out_size, void* d_ws,
                              size_t ws_size, hipStream_t stream) {
  const float* x_this = (const float*)d_in[0];
  const float* x_other = (const float*)d_in[1];
  const float* g_w = (const float*)d_in[2];
  const float* g_b = (const float*)d_in[3];
  const float* th_w = (const float*)d_in[4];
  const float* th_b = (const float*)d_in[5];
  const float* ph_w = (const float*)d_in[6];
  const float* ph_b = (const float*)d_in[7];
  const float* wz_w = (const float*)d_in[8];
  const float* wz_b = (const float*)d_in[9];
  const float* gamma = (const float*)d_in[10];
  const float* beta = (const float*)d_in[11];
  float* out = (float*)d_out;

  float* ws = (float*)d_ws;
  ushort_t* Qb = (ushort_t*)(ws + OFF_QB);
  ushort_t* Kb = (ushort_t*)(ws + OFF_KB);
  ushort_t* Vt = (ushort_t*)(ws + OFF_VT);
  float* WY = ws + OFF_WY;  // aliases Qb/Kb/Vt (dead after attn)
  float* Y = ws + OFF_Y;
  float* AB = ws + OFF_AB;

  hipLaunchKernelGGL(proj_kernel, dim3(NN * BB / 8), dim3(256), 0, stream,
                     x_this, x_other, g_w, g_b, th_w, th_b, ph_w, ph_b,
                     Qb, Kb, Vt);
  hipLaunchKernelGGL(attn_kernel, dim3(NN / 64, BB), dim3(256), 0, stream,
                     Qb, Kb, Vt, Y);
  hipLaunchKernelGGL(wz_kernel, dim3(NN / 64, BB), dim3(256), 0, stream,
                     Y, wz_w, wz_b, WY);
  hipLaunchKernelGGL(stats_kernel, dim3(CC), dim3(256), 0, stream,
                     WY, gamma, beta, AB);
  hipLaunchKernelGGL(norm_kernel, dim3(NN / 64, BB), dim3(256), 0, stream,
                     WY, AB, x_this, out);
}